// Round 5
// baseline (58.777 us; speedup 1.0000x reference)
//
#include <hip/hip_runtime.h>

// Problem constants (from reference)
constexpr int   B  = 32, N = 17;            // batch, keypoints
constexpr int   BN = B * N;                 // 544
constexpr int   H = 128, W = 128, HW = H * W;
constexpr int   BLOCKS_PER_BN = 4;          // 4096 px per block
constexpr int   NBLK = BN * BLOCKS_PER_BN;  // 2176 blocks
constexpr float L_IMG   = 512.0f;
constexpr float STRIDE  = 4.0f;             // L // W
constexpr float START   = STRIDE / 2.0f - 0.5f;     // 1.5
constexpr float INV2SG2 = 1.0f / (2.0f * 8.0f * 8.0f);
constexpr float TRUNCV  = 4.6052f;
constexpr float FXSCALE = 4294967296.0f;    // 2^32 fixed-point scale

// Single fused kernel, fence-free. Cross-block sum via fixed-point u64
// atomicAdd (integer adds are associative -> deterministic). Completion
// ordering via an acq_rel atomic counter (no __threadfence / L2 writeback).
__global__ __launch_bounds__(256)
void heatmap_loss_fused(const float* __restrict__ pred,        // [BN, HW]
                        const float* __restrict__ labels,      // [BN, 2]
                        const float* __restrict__ mask,        // [BN]
                        unsigned long long* __restrict__ acc,  // [1] in ws (zeroed per call)
                        unsigned int* __restrict__ counter,    // [1] in ws (zeroed per call)
                        float* __restrict__ out)               // [1]
{
    const int bid  = blockIdx.x;
    const int bn   = bid >> 2;
    const int q    = bid & 3;
    const int t    = threadIdx.x;
    const int wave = t >> 6;

    float a = 0.0f;
    if (mask[bn] > 0.0f) {   // block-uniform branch; masked kp's 64 KB never read
        const float lx = labels[bn * 2 + 0];
        const float ly = labels[bn * 2 + 1];
        const float cx = fminf(fmaxf((lx * 0.5f + 0.5f) * L_IMG, 0.0f), L_IMG - 1.0f);
        const float cy = fminf(fmaxf((ly * 0.5f + 0.5f) * L_IMG, 0.0f), L_IMG - 1.0f);

        const float4* p4 = reinterpret_cast<const float4*>(pred + (size_t)bn * HW) + q * 1024;

        #pragma unroll
        for (int j = 0; j < 4; ++j) {
            const int f4 = j * 256 + t;          // float4 index within quarter
            const float4 v = p4[f4];
            const int e = (q * 1024 + f4) * 4;   // element index within bn
            const int h = e >> 7;
            const int w = e & 127;
            const float dy  = fmaf(STRIDE, (float)h, START) - cy;
            const float dy2 = dy * dy;
            const float pv[4] = { v.x, v.y, v.z, v.w };
            #pragma unroll
            for (int k = 0; k < 4; ++k) {
                const float dx   = fmaf(STRIDE, (float)(w + k), START) - cx;
                const float d2   = fmaf(dx, dx, dy2);
                const float expo = d2 * INV2SG2;
                const float gt   = (expo > TRUNCV) ? 0.0f : __expf(-expo);
                const float diff = pv[k] - gt;
                a = fmaf(diff, diff, a);
            }
        }
        #pragma unroll
        for (int off = 32; off > 0; off >>= 1)
            a += __shfl_down(a, off, 64);
    }

    __shared__ float sacc[4];
    __shared__ int   s_last;
    if ((t & 63) == 0) sacc[wave] = a;
    __syncthreads();

    if (t == 0) {
        const float part = (sacc[0] + sacc[1] + sacc[2] + sacc[3]) * (1.0f / (float)HW);
        if (part != 0.0f) {
            const unsigned long long fx =
                (unsigned long long)llrintf(part * FXSCALE);
            __hip_atomic_fetch_add(acc, fx, __ATOMIC_RELAXED, __HIP_MEMORY_SCOPE_AGENT);
        }
        // acq_rel RMW: releases our value-add, acquires everyone else's.
        const unsigned int old =
            __hip_atomic_fetch_add(counter, 1u, __ATOMIC_ACQ_REL, __HIP_MEMORY_SCOPE_AGENT);
        s_last = (old == (unsigned int)(NBLK - 1)) ? 1 : 0;
    }
    __syncthreads();

    if (s_last) {   // exactly one block; all value-adds ordered-before via counter chain
        const unsigned long long total =
            __hip_atomic_load(acc, __ATOMIC_RELAXED, __HIP_MEMORY_SCOPE_AGENT);
        float nv = 0.0f;
        for (int i = t; i < BN; i += 256) nv += mask[i];
        #pragma unroll
        for (int off = 32; off > 0; off >>= 1)
            nv += __shfl_down(nv, off, 64);
        __shared__ float sn[4];
        if ((t & 63) == 0) sn[wave] = nv;
        __syncthreads();
        if (t == 0) {
            const float NV = sn[0] + sn[1] + sn[2] + sn[3];
            const float T  = (float)((double)total * (1.0 / 4294967296.0));
            out[0] = (NV > 0.0f) ? (T / fmaxf(NV, 1.0f)) : 0.0f;
        }
    }
}

extern "C" void kernel_launch(void* const* d_in, const int* in_sizes, int n_in,
                              void* d_out, int out_size, void* d_ws, size_t ws_size,
                              hipStream_t stream) {
    const float* pred   = (const float*)d_in[0]; // [B,N,H,W]
    const float* labels = (const float*)d_in[1]; // [B,N,2]
    const float* mask   = (const float*)d_in[2]; // [B,N]
    float* out = (float*)d_out;

    unsigned long long* acc     = (unsigned long long*)d_ws;           // 8 B
    unsigned int*       counter = (unsigned int*)((char*)d_ws + 8);    // 4 B

    // Per-call reset of acc+counter (single 12-byte memset node).
    hipMemsetAsync(d_ws, 0, 12, stream);
    heatmap_loss_fused<<<NBLK, 256, 0, stream>>>(pred, labels, mask, acc, counter, out);
}

// Round 6
// 14.702 us; speedup vs baseline: 3.9979x; 3.9979x over previous
//
#include <hip/hip_runtime.h>

// Problem constants (from reference)
constexpr int   B  = 32, N = 17;            // batch, keypoints
constexpr int   BN = B * N;                 // 544
constexpr int   H = 128, W = 128, HW = H * W;
constexpr int   BLOCKS_PER_BN = 4;          // 4096 px per block
constexpr int   NBLK = BN * BLOCKS_PER_BN;  // 2176 blocks
constexpr int   NSLOT = 32;                 // striped atomic slots (1 line each)
constexpr int   SLOT_BLKS = NBLK / NSLOT;   // 68 blocks per slot
constexpr int   SLOT_STRIDE_U64 = 32;       // 256 B between slots (own cache line)
constexpr float L_IMG   = 512.0f;
constexpr float STRIDE  = 4.0f;             // L // W
constexpr float START   = STRIDE / 2.0f - 0.5f;     // 1.5
constexpr float INV2SG2 = 1.0f / (2.0f * 8.0f * 8.0f);
constexpr float TRUNCV  = 4.6052f;
constexpr float  FXSCALE     = 68719476736.0f;       // 2^36 fixed-point scale
constexpr double INV_FXSCALE = 1.0 / 68719476736.0;
constexpr unsigned long long CNT_ONE = 1ull << 52;   // arrival count in bits 52..63
constexpr unsigned long long VAL_MASK = CNT_ONE - 1; // value in bits 0..51

// Single fused kernel. Cross-block sum via packed {count|fixed-point-value}
// u64 atomics: value and completion-count share one atomic cell, so RELAXED
// ordering is sufficient (no fences). Two-level striping (32 lines -> 1 line)
// keeps same-line RMW serialization to ~68 ops instead of 4352.
__global__ __launch_bounds__(256)
void heatmap_loss_fused(const float* __restrict__ pred,          // [BN, HW]
                        const float* __restrict__ labels,        // [BN, 2]
                        const float* __restrict__ mask,          // [BN]
                        unsigned long long* __restrict__ slots,  // [(NSLOT+1)*32] u64, zeroed per call
                        float* __restrict__ out)                 // [1]
{
    const int bid  = blockIdx.x;
    const int bn   = bid >> 2;
    const int q    = bid & 3;
    const int t    = threadIdx.x;
    const int wave = t >> 6;

    // Every block computes NV redundantly (2 KB, L2-cached) so whichever
    // block finishes last can produce the final scalar immediately.
    float nv = 0.0f;
    for (int i = t; i < BN; i += 256) nv += mask[i];

    float a = 0.0f;
    if (mask[bn] > 0.0f) {   // block-uniform; masked kp's 64 KB never read
        const float lx = labels[bn * 2 + 0];
        const float ly = labels[bn * 2 + 1];
        const float cx = fminf(fmaxf((lx * 0.5f + 0.5f) * L_IMG, 0.0f), L_IMG - 1.0f);
        const float cy = fminf(fmaxf((ly * 0.5f + 0.5f) * L_IMG, 0.0f), L_IMG - 1.0f);

        const float4* p4 = reinterpret_cast<const float4*>(pred + (size_t)bn * HW) + q * 1024;

        #pragma unroll
        for (int j = 0; j < 4; ++j) {
            const int f4 = j * 256 + t;          // float4 index within quarter
            const float4 v = p4[f4];
            const int e = (q * 1024 + f4) * 4;   // element index within bn
            const int h = e >> 7;
            const int w = e & 127;
            const float dy  = fmaf(STRIDE, (float)h, START) - cy;
            const float dy2 = dy * dy;
            const float pv[4] = { v.x, v.y, v.z, v.w };
            #pragma unroll
            for (int k = 0; k < 4; ++k) {
                const float dx   = fmaf(STRIDE, (float)(w + k), START) - cx;
                const float d2   = fmaf(dx, dx, dy2);
                const float expo = d2 * INV2SG2;
                const float gt   = (expo > TRUNCV) ? 0.0f : __expf(-expo);
                const float diff = pv[k] - gt;
                a = fmaf(diff, diff, a);
            }
        }
    }

    // Reduce a and nv across the block (shuffle within wave, LDS across waves).
    #pragma unroll
    for (int off = 32; off > 0; off >>= 1) {
        a  += __shfl_down(a,  off, 64);
        nv += __shfl_down(nv, off, 64);
    }
    __shared__ float sacc[4], snv[4];
    if ((t & 63) == 0) { sacc[wave] = a; snv[wave] = nv; }
    __syncthreads();

    if (t == 0) {
        const float part = (sacc[0] + sacc[1] + sacc[2] + sacc[3]) * (1.0f / (float)HW);
        const float NV   = snv[0] + snv[1] + snv[2] + snv[3];

        const unsigned long long fx =
            (unsigned long long)llrintf(part * FXSCALE);     // < 2^46, no field overflow
        const unsigned long long packed = CNT_ONE + fx;

        unsigned long long* slot = slots + (size_t)(bid & (NSLOT - 1)) * SLOT_STRIDE_U64;
        const unsigned long long old =
            __hip_atomic_fetch_add(slot, packed, __ATOMIC_RELAXED, __HIP_MEMORY_SCOPE_AGENT);

        if ((old >> 52) == (unsigned long long)(SLOT_BLKS - 1)) {
            // Last arriver in this slot: fetch-add return gives the full slot sum.
            const unsigned long long slot_sum = (old + packed) & VAL_MASK;
            const unsigned long long spacked  = CNT_ONE + slot_sum;
            unsigned long long* super_cell = slots + (size_t)NSLOT * SLOT_STRIDE_U64;
            const unsigned long long sold =
                __hip_atomic_fetch_add(super_cell, spacked, __ATOMIC_RELAXED, __HIP_MEMORY_SCOPE_AGENT);
            if ((sold >> 52) == (unsigned long long)(NSLOT - 1)) {
                const unsigned long long total = (sold + spacked) & VAL_MASK;
                const double T = (double)total * INV_FXSCALE;
                out[0] = (NV > 0.0f) ? (float)(T / (double)fmaxf(NV, 1.0f)) : 0.0f;
            }
        }
    }
}

extern "C" void kernel_launch(void* const* d_in, const int* in_sizes, int n_in,
                              void* d_out, int out_size, void* d_ws, size_t ws_size,
                              hipStream_t stream) {
    const float* pred   = (const float*)d_in[0]; // [B,N,H,W]
    const float* labels = (const float*)d_in[1]; // [B,N,2]
    const float* mask   = (const float*)d_in[2]; // [B,N]
    float* out = (float*)d_out;

    unsigned long long* slots = (unsigned long long*)d_ws; // (NSLOT+1)*256 B

    // Per-call reset of all slot cells + super cell (one small memset node).
    hipMemsetAsync(d_ws, 0, (NSLOT + 1) * SLOT_STRIDE_U64 * sizeof(unsigned long long), stream);
    heatmap_loss_fused<<<NBLK, 256, 0, stream>>>(pred, labels, mask, slots, out);
}